// Round 4
// baseline (82.075 us; speedup 1.0000x reference)
//
#include <hip/hip_runtime.h>

#define NCLS 19
#define BINS 51
#define NPIX 4096
#define NFEAT 256
#define NTHR 512
#define NWAVE 8
#define CHUNKS 64      // NPIX / 64
#define CPW 8          // chunks per wave
#define TWO_PI_F 6.2831853071795864769f
#define LOG2E_F 1.4426950408889634f

#define EXP2F(v) __builtin_amdgcn_exp2f(v)

// ws layout: float partial[NFEAT] @ 0 ; int counter @ 1024
__global__ __launch_bounds__(NTHR)
void histloss_k(const float* __restrict__ x, const int* __restrict__ lab,
                float* __restrict__ partial, int* __restrict__ counter,
                float* __restrict__ out) {
    const int f    = blockIdx.x;
    const int tid  = threadIdx.x;
    const int lane = tid & 63;
    const int wave = tid >> 6;

    __shared__ __align__(16) float xs[NPIX + 64];   // class-compacted x, padded segs
    __shared__ int   cnt[CHUNKS][NCLS];             // per-chunk class prefix
    __shared__ int   base4[NCLS + 1];               // padded segment bases
    __shared__ int   n_arr[NCLS];
    __shared__ float miu_arr[NCLS], var_arr[NCLS];
    __shared__ float s_acc[NCLS][4][64];            // KDE partials per (c, quarter)
    __shared__ float s_loss[NCLS];
    __shared__ double s_red[NWAVE];
    __shared__ int   s_last;

    int   vlab[CPW];
    float vx[CPW];
    const float* xrow = x + (size_t)f * NPIX;

    // ---- Phase A: load labels + x (kept in regs), per-chunk per-class counts ----
    #pragma unroll
    for (int k = 0; k < CPW; ++k) {
        int ch = wave + k * NWAVE;
        int p  = ch * 64 + lane;
        vlab[k] = lab[p];
        vx[k]   = xrow[p];
    }
    #pragma unroll
    for (int k = 0; k < CPW; ++k) {
        int ch = wave + k * NWAVE;
        int v  = vlab[k];
        for (int c = 1; c < NCLS; ++c) {
            unsigned long long m = __ballot(v == c);
            if (lane == 0) cnt[ch][c] = (int)__popcll(m);
        }
    }
    __syncthreads();

    // ---- Phase B: per-class chunk prefix + padded bases ----
    if (tid >= 1 && tid < NCLS) {
        int c = tid, run = 0;
        for (int ch = 0; ch < CHUNKS; ++ch) { int t = cnt[ch][c]; cnt[ch][c] = run; run += t; }
        n_arr[c] = run;
    }
    __syncthreads();
    if (tid == 0) {
        int run = 0;
        for (int c = 1; c < NCLS; ++c) { base4[c] = run; run += (n_arr[c] + 3) & ~3; }
        base4[NCLS] = run;
    }
    __syncthreads();

    // ---- Phase C: rank-based scatter into class segments + sentinel pads ----
    #pragma unroll
    for (int k = 0; k < CPW; ++k) {
        int ch = wave + k * NWAVE;
        int v  = vlab[k];
        for (int c = 1; c < NCLS; ++c) {
            unsigned long long m = __ballot(v == c);
            if (v == c) {
                int rank = (int)__popcll(m & ((1ull << lane) - 1ull));
                xs[base4[c] + cnt[ch][c] + rank] = vx[k];
            }
        }
    }
    if (tid >= 1 && tid < NCLS) {
        int c = tid, n = n_arr[c], n4 = (n + 3) & ~3;
        for (int j = n; j < n4; ++j) xs[base4[c] + j] = 1e19f;  // exp2 -> 0
    }
    __syncthreads();

    // ---- Phase S: per-class stats (class c -> wave (c-1)%8) ----
    for (int c = wave + 1; c < NCLS; c += NWAVE) {
        int n = n_arr[c], b = base4[c];
        float s1 = 0.f, s2 = 0.f;
        for (int i = lane; i < n; i += 64) { float v = xs[b + i]; s1 += v; s2 += v * v; }
        for (int off = 32; off; off >>= 1) {
            s1 += __shfl_xor(s1, off, 64);
            s2 += __shfl_xor(s2, off, 64);
        }
        if (lane == 0 && n > 0) {
            float fn  = (float)n;
            float miu = s1 / fn;
            float var = fmaxf(s2 / fn - miu * miu, 1e-12f);
            miu_arr[c] = miu;
            var_arr[c] = var;
        }
    }
    __syncthreads();

    // ---- Phase D: KDE. 72 items (class, quarter) over 8 waves; lane = bin ----
    const float binv = -5.0f + 0.2f * (float)lane;
    for (int item = wave; item < 18 * 4; item += NWAVE) {
        int c  = 1 + (item >> 2);
        int q  = item & 3;
        int n  = n_arr[c];
        int b  = base4[c];
        int N4 = (n + 3) & ~3;
        float coef2 = (n > 0) ? (-0.5f / (var_arr[c] * 0.04f)) * LOG2E_F : 0.f;
        float a0 = 0.f, a1 = 0.f, a2 = 0.f, a3 = 0.f;
        for (int i = q * 4; i < N4; i += 16) {
            float4 v = *(const float4*)&xs[b + i];      // LDS broadcast, 16B aligned
            float d0 = binv - v.x, d1 = binv - v.y, d2 = binv - v.z, d3 = binv - v.w;
            a0 += EXP2F(coef2 * d0 * d0);
            a1 += EXP2F(coef2 * d1 * d1);
            a2 += EXP2F(coef2 * d2 * d2);
            a3 += EXP2F(coef2 * d3 * d3);
        }
        s_acc[c][q][lane] = (a0 + a1) + (a2 + a3);
    }
    __syncthreads();

    // ---- Phase E: per-class normalize + smooth-L1 (class c -> wave (c-1)%8) ----
    for (int c = wave + 1; c < NCLS; c += NWAVE) {
        int n = n_arr[c];
        if (n == 0) { if (lane == 0) s_loss[c] = 0.f; continue; }
        float kde = s_acc[c][0][lane] + s_acc[c][1][lane] + s_acc[c][2][lane] + s_acc[c][3][lane];
        float var = var_arr[c], miu = miu_arr[c];
        float vs  = var * 0.04f;
        float dt  = binv - miu;
        float tg  = EXP2F(((-0.5f / var) * LOG2E_F) * dt * dt);
        if (lane >= BINS) { kde = 0.f; tg = 0.f; }
        float sv = kde * rsqrtf(TWO_PI_F * vs);
        float tt = tg  * rsqrtf(TWO_PI_F * var);
        float ssum = sv, tsum = tt;
        for (int off = 32; off; off >>= 1) {
            ssum += __shfl_xor(ssum, off, 64);
            tsum += __shfl_xor(tsum, off, 64);
        }
        float hist  = sv / fmaxf(ssum, 1e-12f);
        float tnorm = tt / tsum;
        float diff  = hist - tnorm;
        float ad    = fabsf(diff);
        float sl1   = (ad < 1.0f) ? 0.5f * diff * diff : (ad - 0.5f);
        if (lane >= BINS) sl1 = 0.f;
        for (int off = 32; off; off >>= 1) sl1 += __shfl_xor(sl1, off, 64);
        if (lane == 0) s_loss[c] = sl1;
    }
    __syncthreads();

    if (tid == 0) {
        float acc = 0.f;
        for (int c = 1; c < NCLS; ++c) acc += s_loss[c];
        partial[f] = acc;
    }

    // ---- Phase F: last block reduces all features (deterministic) ----
    __threadfence();
    if (tid == 0) {
        int old = atomicAdd(counter, 1);
        s_last = (old == NFEAT - 1) ? 1 : 0;
    }
    __syncthreads();
    if (s_last) {
        __threadfence();
        double s = 0.0;
        if (tid < NFEAT) s = (double)partial[tid];
        for (int off = 32; off; off >>= 1) s += __shfl_xor(s, off, 64);
        if (lane == 0) s_red[wave] = s;
        __syncthreads();
        if (tid == 0) {
            double tot = 0.0;
            for (int w = 0; w < NWAVE; ++w) tot += s_red[w];
            int active = 0;
            for (int c = 1; c < NCLS; ++c) active += (n_arr[c] > 0) ? 1 : 0;
            double loss = tot / (double)(NFEAT * BINS) / ((double)active + 1e-12);
            out[0] = (float)loss;
        }
    }
}

extern "C" void kernel_launch(void* const* d_in, const int* in_sizes, int n_in,
                              void* d_out, int out_size, void* d_ws, size_t ws_size,
                              hipStream_t stream) {
    const float* x   = (const float*)d_in[0];
    const int*   lab = (const int*)d_in[1];
    float* out       = (float*)d_out;
    float* partial   = (float*)d_ws;
    int*   counter   = (int*)((char*)d_ws + 1024);

    (void)hipMemsetAsync(counter, 0, sizeof(int), stream);   // ticket reset each replay
    hipLaunchKernelGGL(histloss_k, dim3(NFEAT), dim3(NTHR), 0, stream,
                       x, lab, partial, counter, out);
}

// Round 5
// 30.257 us; speedup vs baseline: 2.7126x; 2.7126x over previous
//
#include <hip/hip_runtime.h>

#define NCLS 19
#define BINS 51
#define NPIX 4096
#define NFEAT 256
#define CHUNKS 64
#define CG 6          // class groups (blocks per feature)
#define CPB 3         // classes per block
#define TWO_PI_F 6.2831853071795864769f
#define LOG2E_F 1.4426950408889634f
#define EXP2F(v) __builtin_amdgcn_exp2f(v)

// ws layout: float partial[NFEAT*CG] @ 0 ; int ncls[32] @ 8192
__global__ __launch_bounds__(256)
void hist_main(const float* __restrict__ x, const int* __restrict__ lab,
               float* __restrict__ partial, int* __restrict__ ncls) {
    const int f    = blockIdx.x;
    const int g    = blockIdx.y;
    const int tid  = threadIdx.x;
    const int lane = tid & 63;
    const int wave = tid >> 6;          // 0..3
    const int c0   = g * CPB + 1;       // first class of this block

    __shared__ __align__(16) float xs[NPIX + 4 * CPB];
    __shared__ int   cnt[CHUNKS][CPB];  // chunk counts -> chunk-exclusive prefix
    __shared__ int   n_s[CPB], base_s[CPB];
    __shared__ float miu_s[CPB], var_s[CPB];
    __shared__ float s_acc[CPB][4][64];
    __shared__ float s_loss[CPB];

    // ---- A: per-chunk per-class counts (wave-strided chunks, coalesced 256B) ----
    #pragma unroll
    for (int k = 0; k < 16; ++k) {
        int ch = wave + 4 * k;
        int v  = lab[ch * 64 + lane];
        #pragma unroll
        for (int j = 0; j < CPB; ++j) {
            unsigned long long m = __ballot(v == c0 + j);
            if (lane == 0) cnt[ch][j] = (int)__popcll(m);
        }
    }
    __syncthreads();

    // ---- B: per-class exclusive prefix over 64 chunks via wave scan ----
    if (wave < CPB) {
        int v = cnt[lane][wave];
        int s = v;
        #pragma unroll
        for (int off = 1; off < 64; off <<= 1) {
            int t = __shfl_up(s, off, 64);
            if (lane >= off) s += t;
        }
        cnt[lane][wave] = s - v;        // exclusive
        if (lane == 63) n_s[wave] = s;  // class total
    }
    __syncthreads();
    if (tid == 0) {
        int run = 0;
        #pragma unroll
        for (int j = 0; j < CPB; ++j) { base_s[j] = run; run += (n_s[j] + 3) & ~3; }
        if (f == 0) {
            #pragma unroll
            for (int j = 0; j < CPB; ++j) ncls[c0 + j] = n_s[j];
        }
    }
    __syncthreads();

    // ---- C: rank-based scatter into padded class segments ----
    const float* xrow = x + (size_t)f * NPIX;
    #pragma unroll
    for (int k = 0; k < 16; ++k) {
        int   ch = wave + 4 * k;
        int   p  = ch * 64 + lane;
        int   v  = lab[p];              // L1-hit reload
        float xv = xrow[p];
        #pragma unroll
        for (int j = 0; j < CPB; ++j) {
            unsigned long long m = __ballot(v == c0 + j);
            if (v == c0 + j) {
                int rank = (int)__popcll(m & ((1ull << lane) - 1ull));
                xs[base_s[j] + cnt[ch][j] + rank] = xv;
            }
        }
    }
    if (wave < CPB) {                   // sentinel pads: exp2 -> 0
        int n = n_s[wave], pad = ((n + 3) & ~3) - n;
        if (lane < pad) xs[base_s[wave] + n + lane] = 1e19f;
    }
    __syncthreads();

    // ---- S: per-class stats (wave j <-> class j) ----
    if (wave < CPB) {
        int n = n_s[wave], b = base_s[wave];
        float s1 = 0.f, s2 = 0.f;
        for (int i = lane; i < n; i += 64) { float v = xs[b + i]; s1 += v; s2 += v * v; }
        #pragma unroll
        for (int off = 32; off; off >>= 1) {
            s1 += __shfl_xor(s1, off, 64);
            s2 += __shfl_xor(s2, off, 64);
        }
        if (lane == 0 && n > 0) {
            float fn  = (float)n;
            float miu = s1 / fn;
            miu_s[wave] = miu;
            var_s[wave] = fmaxf(s2 / fn - miu * miu, 1e-12f);
        }
    }
    __syncthreads();

    // ---- D: KDE. quarter = wave; classes looped; lane = bin; 4 exp chains ----
    const float binv = -5.0f + 0.2f * (float)lane;
    #pragma unroll
    for (int j = 0; j < CPB; ++j) {
        int n = n_s[j], b = base_s[j], N4 = (n + 3) & ~3;
        float coef2 = (n > 0) ? (-0.5f / (var_s[j] * 0.04f)) * LOG2E_F : 0.f;
        float a0 = 0.f, a1 = 0.f, a2 = 0.f, a3 = 0.f;
        for (int i = wave * 4; i < N4; i += 16) {
            float4 v = *(const float4*)&xs[b + i];    // LDS broadcast, 16B aligned
            float d0 = binv - v.x, d1 = binv - v.y, d2 = binv - v.z, d3 = binv - v.w;
            a0 += EXP2F(coef2 * d0 * d0);
            a1 += EXP2F(coef2 * d1 * d1);
            a2 += EXP2F(coef2 * d2 * d2);
            a3 += EXP2F(coef2 * d3 * d3);
        }
        s_acc[j][wave][lane] = (a0 + a1) + (a2 + a3);
    }
    __syncthreads();

    // ---- E: per-class normalize + smooth-L1 (wave j <-> class j) ----
    if (wave < CPB) {
        int j = wave, n = n_s[j];
        if (n == 0) {
            if (lane == 0) s_loss[j] = 0.f;
        } else {
            float kde = s_acc[j][0][lane] + s_acc[j][1][lane] +
                        s_acc[j][2][lane] + s_acc[j][3][lane];
            float var = var_s[j], miu = miu_s[j];
            float vs  = var * 0.04f;
            float dt  = binv - miu;
            float tg  = EXP2F(((-0.5f / var) * LOG2E_F) * dt * dt);
            if (lane >= BINS) { kde = 0.f; tg = 0.f; }
            float sv = kde * rsqrtf(TWO_PI_F * vs);
            float tt = tg  * rsqrtf(TWO_PI_F * var);
            float ssum = sv, tsum = tt;
            #pragma unroll
            for (int off = 32; off; off >>= 1) {
                ssum += __shfl_xor(ssum, off, 64);
                tsum += __shfl_xor(tsum, off, 64);
            }
            float hist  = sv / fmaxf(ssum, 1e-12f);
            float tnorm = tt / tsum;
            float diff  = hist - tnorm;
            float ad    = fabsf(diff);
            float sl1   = (ad < 1.0f) ? 0.5f * diff * diff : (ad - 0.5f);
            if (lane >= BINS) sl1 = 0.f;
            #pragma unroll
            for (int off = 32; off; off >>= 1) sl1 += __shfl_xor(sl1, off, 64);
            if (lane == 0) s_loss[j] = sl1;
        }
    }
    __syncthreads();

    if (tid == 0)
        partial[g * NFEAT + f] = s_loss[0] + s_loss[1] + s_loss[2];
}

__global__ __launch_bounds__(256)
void hist_final(const float* __restrict__ partial, const int* __restrict__ ncls,
                float* __restrict__ out) {
    const int tid = threadIdx.x, lane = tid & 63, wave = tid >> 6;
    __shared__ double sd[4];

    double s = 0.0;
    for (int i = tid; i < NFEAT * CG; i += 256) s += (double)partial[i];
    #pragma unroll
    for (int off = 32; off; off >>= 1) s += __shfl_xor(s, off, 64);
    if (lane == 0) sd[wave] = s;
    __syncthreads();
    if (tid == 0) {
        double tot = sd[0] + sd[1] + sd[2] + sd[3];
        int active = 0;
        for (int c = 1; c < NCLS; ++c) active += (ncls[c] > 0) ? 1 : 0;
        double loss = tot / (double)(NFEAT * BINS) / ((double)active + 1e-12);
        out[0] = (float)loss;
    }
}

extern "C" void kernel_launch(void* const* d_in, const int* in_sizes, int n_in,
                              void* d_out, int out_size, void* d_ws, size_t ws_size,
                              hipStream_t stream) {
    const float* x   = (const float*)d_in[0];
    const int*   lab = (const int*)d_in[1];
    float* out       = (float*)d_out;
    float* partial   = (float*)d_ws;
    int*   ncls      = (int*)((char*)d_ws + 8192);

    hipLaunchKernelGGL(hist_main, dim3(NFEAT, CG), dim3(256), 0, stream,
                       x, lab, partial, ncls);
    hipLaunchKernelGGL(hist_final, dim3(1), dim3(256), 0, stream,
                       partial, ncls, out);
}